// Round 2
// baseline (26.955 us; speedup 1.0000x reference)
//
#include <hip/hip_runtime.h>

// Morph2D: reference = extract 3x3 SAME patches, *se, sort over 144, sum.
// sum∘sort == sum  =>  exactly a 3x3 conv x[B,H,W,C] * se[3,3,C,F].
// Output flat layout is [B, F, H*W] (the reference reshape is a raw
// reinterpret, not a transpose).
//
// Round 2: one thread per OUTPUT element (pixel, f) instead of per pixel.
//  - 589824 threads = 9216 waves = exactly 9 waves/SIMD -> balanced
//    (previous 1152 waves/1024 SIMDs had ~2x tail imbalance).
//  - 144 FMAs/thread as float4 elementwise -> v_pk_fma_f32.
//  - se staged in LDS transposed to [tap][f][c] so per-f reads are
//    contiguous float4; all lanes in a wave share f -> LDS broadcast.
//  - gid == flat output index -> stores perfectly coalesced.

#define Bc 2
#define Hc 192
#define Wc 192
#define Cc 16
#define Fc 8
#define HWc (Hc * Wc)

__global__ __launch_bounds__(256) void morph2d_conv(
    const float* __restrict__ x,    // [B,H,W,C]
    const float* __restrict__ se,   // [3,3,C,F]
    float* __restrict__ out)        // flat [B,F,HW]
{
    __shared__ float s_se[9][Fc][Cc];  // transposed: [tap][f][c], 4.5 KiB
    for (int i = threadIdx.x; i < 9 * Cc * Fc; i += 256) {
        int tap = i / (Cc * Fc);
        int rem = i - tap * Cc * Fc;
        int c   = rem / Fc;            // source layout [tap][c][f]
        int f   = rem - c * Fc;
        s_se[tap][f][c] = se[i];
    }
    __syncthreads();

    int gid = blockIdx.x * 256 + threadIdx.x;   // flat output index [B,F,HW]
    int b   = gid / (Fc * HWc);
    int rem = gid - b * (Fc * HWc);
    int f   = rem / HWc;
    int hw  = rem - f * HWc;
    int h   = hw / Wc;
    int w   = hw - h * Wc;

    float4 acc = {0.f, 0.f, 0.f, 0.f};
    const float* xb = x + (long)b * HWc * Cc;

    #pragma unroll
    for (int kh = 0; kh < 3; ++kh) {
        int hy = h + kh - 1;
        if (hy < 0 || hy >= Hc) continue;
        #pragma unroll
        for (int kw = 0; kw < 3; ++kw) {
            int wx = w + kw - 1;
            if (wx < 0 || wx >= Wc) continue;
            const float* xp = xb + (hy * Wc + wx) * Cc;
            const float* sp = &s_se[kh * 3 + kw][f][0];  // wave-uniform
            #pragma unroll
            for (int c4 = 0; c4 < Cc / 4; ++c4) {
                float4 xv = *reinterpret_cast<const float4*>(xp + c4 * 4);
                float4 sv = *reinterpret_cast<const float4*>(sp + c4 * 4);
                acc.x += xv.x * sv.x;
                acc.y += xv.y * sv.y;
                acc.z += xv.z * sv.z;
                acc.w += xv.w * sv.w;
            }
        }
    }

    out[gid] = (acc.x + acc.y) + (acc.z + acc.w);
}

extern "C" void kernel_launch(void* const* d_in, const int* in_sizes, int n_in,
                              void* d_out, int out_size, void* d_ws, size_t ws_size,
                              hipStream_t stream) {
    const float* x  = (const float*)d_in[0];
    const float* se = (const float*)d_in[1];
    // d_in[2] = ranks: unused by the reference's actual output.
    float* out = (float*)d_out;

    int total = Bc * Fc * HWc;               // 589824 output elements
    int block = 256;
    int grid  = (total + block - 1) / block; // 2304 blocks = 9/CU exactly
    morph2d_conv<<<grid, block, 0, stream>>>(x, se, out);
}

// Round 3
// 12.872 us; speedup vs baseline: 2.0941x; 2.0941x over previous
//
#include <hip/hip_runtime.h>

// Morph2D: reference = extract 3x3 SAME patches, *se, sort over 144, sum.
// sum∘sort == sum  =>  exactly a 3x3 conv x[B,H,W,C] * se[3,3,C,F].
// Output flat layout is [B, F, H*W] (reference reshape = raw reinterpret).
//
// Round 3: thread-per-pixel (1x minimal x traffic, 41k wave-loads total) with
//  - se read DIRECTLY from global with wave-uniform literal offsets ->
//    compiler emits s_load into SGPRs (scalar pipe, parallel to VALU,
//    K$-cached, no LDS, no VGPR cost). Round 1's LDS path forced 288
//    per-thread ds_read_b32 + prevented scalar promotion.
//  - branchless borders (clamp + mask-mul) -> straight-line fully-unrolled
//    body, all 36 global_load_dwordx4 batched in flight (round 1's border
//    branches serialized them at HBM latency with only 1.125 waves/SIMD).

#define Bc 2
#define Hc 192
#define Wc 192
#define Cc 16
#define Fc 8
#define HWc (Hc * Wc)

__global__ __launch_bounds__(256) void morph2d_conv(
    const float* __restrict__ x,    // [B,H,W,C]
    const float* __restrict__ se,   // [3,3,C,F]  (f fastest)
    float* __restrict__ out)        // flat [B,F,HW]
{
    int gid = blockIdx.x * 256 + threadIdx.x;   // over B*H*W (exact: 288*256)
    int b   = gid / HWc;
    int hw  = gid - b * HWc;
    int h   = hw / Wc;
    int w   = hw - h * Wc;

    float4 acc0 = {0.f, 0.f, 0.f, 0.f};   // f = 0..3
    float4 acc1 = {0.f, 0.f, 0.f, 0.f};   // f = 4..7

    const float* xb = x + (size_t)b * HWc * Cc;

    #pragma unroll
    for (int kh = 0; kh < 3; ++kh) {
        int hy = h + kh - 1;
        int hc = min(max(hy, 0), Hc - 1);
        float mh = ((unsigned)hy < (unsigned)Hc) ? 1.f : 0.f;
        #pragma unroll
        for (int kw = 0; kw < 3; ++kw) {
            int wx = w + kw - 1;
            int wc = min(max(wx, 0), Wc - 1);
            float m = ((unsigned)wx < (unsigned)Wc) ? mh : 0.f;

            const float* xp = xb + (hc * Wc + wc) * Cc;
            const float* sp = se + (kh * 3 + kw) * Cc * Fc;  // uniform base

            #pragma unroll
            for (int c4 = 0; c4 < Cc / 4; ++c4) {
                float4 xv = *reinterpret_cast<const float4*>(xp + c4 * 4);
                float xm[4] = {xv.x * m, xv.y * m, xv.z * m, xv.w * m};
                #pragma unroll
                for (int cc = 0; cc < 4; ++cc) {
                    int c = c4 * 4 + cc;
                    // uniform literal offsets -> s_load, SGPR operands
                    float4 s0 = *reinterpret_cast<const float4*>(sp + c * Fc + 0);
                    float4 s1 = *reinterpret_cast<const float4*>(sp + c * Fc + 4);
                    float xs = xm[cc];
                    acc0.x += xs * s0.x;  acc0.y += xs * s0.y;
                    acc0.z += xs * s0.z;  acc0.w += xs * s0.w;
                    acc1.x += xs * s1.x;  acc1.y += xs * s1.y;
                    acc1.z += xs * s1.z;  acc1.w += xs * s1.w;
                }
            }
        }
    }

    // out flat = [B, F, HW]; consecutive threads (hw) -> coalesced per f
    float* ob = out + (size_t)b * Fc * HWc + hw;
    ob[0 * HWc] = acc0.x;  ob[1 * HWc] = acc0.y;
    ob[2 * HWc] = acc0.z;  ob[3 * HWc] = acc0.w;
    ob[4 * HWc] = acc1.x;  ob[5 * HWc] = acc1.y;
    ob[6 * HWc] = acc1.z;  ob[7 * HWc] = acc1.w;
}

extern "C" void kernel_launch(void* const* d_in, const int* in_sizes, int n_in,
                              void* d_out, int out_size, void* d_ws, size_t ws_size,
                              hipStream_t stream) {
    const float* x  = (const float*)d_in[0];
    const float* se = (const float*)d_in[1];
    // d_in[2] = ranks: unused by the reference's actual output.
    float* out = (float*)d_out;

    int total = Bc * HWc;                    // 73728
    int block = 256;
    int grid  = (total + block - 1) / block; // 288
    morph2d_conv<<<grid, block, 0, stream>>>(x, se, out);
}

// Round 4
// 11.080 us; speedup vs baseline: 2.4327x; 1.1617x over previous
//
#include <hip/hip_runtime.h>

// Morph2D: sum∘sort == sum => 3x3 SAME conv x[B,H,W,C] * se[3,3,C,F].
// Output flat = [B, F, H*W] (reference reshape = raw reinterpret).
//
// Round 4: c4-split lanes. lane = pixel*4 + c4; each lane owns 4 channels.
//  - x loads: one dwordx4 per tap per lane; wave = 16 px * 64B contiguous
//    -> 8 granules per load (round 3's 64B-stride pattern cost 32) = 4x less
//    L1 array traffic.
//  - 4608 waves = 4.5/SIMD (vs 1.125): latency hidden, tail imbalance 11%.
//  - se in LDS, per-c4 plane stride 296 dwords: the 4 lane-variant read
//    addresses hit banks {0,8,16,24} -> conflict-free 16-lane broadcast.
//  - channel reduce: 2x shfl_xor within the 4-lane quad; each lane stores
//    its f-pair (f = c4*2, c4*2+1), 64B segments tiled densely by adjacent
//    waves.

#define Bc 2
#define Hc 192
#define Wc 192
#define Cc 16
#define Fc 8
#define HWc (Hc * Wc)
#define PLANE 296   // per-c4 se plane stride (dwords): 9*32=288 + 8 pad

__global__ __launch_bounds__(256) void morph2d_conv(
    const float* __restrict__ x,    // [B,H,W,C]
    const float* __restrict__ se,   // [3,3,C,F] (f fastest)
    float* __restrict__ out)        // flat [B,F,HW]
{
    __shared__ float s_se[4 * PLANE];  // 4.6 KiB
    for (int i = threadIdx.x; i < 9 * Cc * Fc; i += 256) {
        int tap = i / (Cc * Fc);
        int rem = i - tap * Cc * Fc;
        int c   = rem / Fc;
        int f   = rem - c * Fc;
        int c4  = c >> 2, j = c & 3;
        s_se[c4 * PLANE + tap * 32 + j * 8 + f] = se[i];
    }
    __syncthreads();

    int tid = blockIdx.x * 256 + threadIdx.x;   // 294912 threads exact
    int pix = tid >> 2;                          // global pixel
    int c4  = tid & 3;
    int b   = pix / HWc;
    int hw  = pix - b * HWc;
    int h   = hw / Wc;
    int w   = hw - h * Wc;   // blocks = 64 consecutive px, never straddle a row

    const float* xb = x + (size_t)b * HWc * Cc + c4 * 4;
    const float* sb = s_se + c4 * PLANE;

    float a0x=0.f,a0y=0.f,a0z=0.f,a0w=0.f;   // f 0..3 (partial over 4 ch)
    float a1x=0.f,a1y=0.f,a1z=0.f,a1w=0.f;   // f 4..7

    #pragma unroll
    for (int kh = 0; kh < 3; ++kh) {
        int hy = h + kh - 1;
        int hc = min(max(hy, 0), Hc - 1);
        bool okh = (unsigned)hy < (unsigned)Hc;
        #pragma unroll
        for (int kw = 0; kw < 3; ++kw) {
            int wx = w + kw - 1;
            int wc = min(max(wx, 0), Wc - 1);
            float m = (okh && (unsigned)wx < (unsigned)Wc) ? 1.f : 0.f;

            float4 xv = *reinterpret_cast<const float4*>(xb + (hc * Wc + wc) * Cc);
            float xj[4] = {xv.x * m, xv.y * m, xv.z * m, xv.w * m};

            const float* sp = sb + (kh * 3 + kw) * 32;
            #pragma unroll
            for (int j = 0; j < 4; ++j) {
                float4 s0 = *reinterpret_cast<const float4*>(sp + j * 8);
                float4 s1 = *reinterpret_cast<const float4*>(sp + j * 8 + 4);
                float xs = xj[j];
                a0x += xs * s0.x;  a0y += xs * s0.y;
                a0z += xs * s0.z;  a0w += xs * s0.w;
                a1x += xs * s1.x;  a1y += xs * s1.y;
                a1z += xs * s1.z;  a1w += xs * s1.w;
            }
        }
    }

    // reduce over the 4-lane quad (channel groups)
    a0x += __shfl_xor(a0x, 1); a0x += __shfl_xor(a0x, 2);
    a0y += __shfl_xor(a0y, 1); a0y += __shfl_xor(a0y, 2);
    a0z += __shfl_xor(a0z, 1); a0z += __shfl_xor(a0z, 2);
    a0w += __shfl_xor(a0w, 1); a0w += __shfl_xor(a0w, 2);
    a1x += __shfl_xor(a1x, 1); a1x += __shfl_xor(a1x, 2);
    a1y += __shfl_xor(a1y, 1); a1y += __shfl_xor(a1y, 2);
    a1z += __shfl_xor(a1z, 1); a1z += __shfl_xor(a1z, 2);
    a1w += __shfl_xor(a1w, 1); a1w += __shfl_xor(a1w, 2);

    // lane stores f-pair (c4*2, c4*2+1); static selects (no dynamic indexing)
    float v0 = (c4 & 2) ? ((c4 & 1) ? a1z : a1x) : ((c4 & 1) ? a0z : a0x);
    float v1 = (c4 & 2) ? ((c4 & 1) ? a1w : a1y) : ((c4 & 1) ? a0w : a0y);

    float* ob = out + (size_t)b * Fc * HWc + hw;
    int f0 = c4 * 2;
    ob[(size_t)f0 * HWc]       = v0;
    ob[(size_t)(f0 + 1) * HWc] = v1;
}

extern "C" void kernel_launch(void* const* d_in, const int* in_sizes, int n_in,
                              void* d_out, int out_size, void* d_ws, size_t ws_size,
                              hipStream_t stream) {
    const float* x  = (const float*)d_in[0];
    const float* se = (const float*)d_in[1];
    // d_in[2] = ranks: unused by the reference's actual output.
    float* out = (float*)d_out;

    int total = Bc * HWc * 4;                // 294912 threads (4 per pixel)
    int block = 256;
    int grid  = total / block;               // 1152 blocks = 4.5/CU
    morph2d_conv<<<grid, block, 0, stream>>>(x, se, out);
}